// Round 13
// baseline (713.927 us; speedup 1.0000x reference)
//
#include <hip/hip_runtime.h>
#include <hip/hip_bf16.h>

#define LRELU_ALPHA 0.3f
#define LN_EPS 1e-3f
#define G 768          // persistent grid: 3 blocks/CU x 256 CUs (see launch_bounds)
#define DIV_TI 8
#define DIV_JC 4

typedef short bf16x8 __attribute__((ext_vector_type(8)));
typedef float f32x4 __attribute__((ext_vector_type(4)));

static __device__ __forceinline__ unsigned short f2bf(float f) {
    union { float f; unsigned u; } v; v.f = f;
    unsigned r = v.u + 0x7fffu + ((v.u >> 16) & 1u);  // RNE
    return (unsigned short)(r >> 16);
}

// async 16B global -> LDS (DMA). LDS dest = wave-uniform base + lane*16.
#define ASYNC_CP16(gsrc, ldst)                                                  \
    __builtin_amdgcn_global_load_lds(                                           \
        (const __attribute__((address_space(1))) unsigned int*)(gsrc),          \
        (__attribute__((address_space(3))) unsigned int*)(ldst), 16, 0, 0)

// Grid-wide barrier: single-use counter per barrier (no sense reversal; memset
// to 0 before launch). Release: __threadfence (device scope, L2 wb on gfx950)
// then atomicAdd; acquire: spin on device-scope atomic read, then fence.
static __device__ __forceinline__ void grid_barrier(unsigned* c) {
    __syncthreads();
    if (threadIdx.x == 0) {
        __threadfence();
        atomicAdd(c, 1u);
        while (atomicAdd(c, 0u) < (unsigned)G) __builtin_amdgcn_s_sleep(8);
        __threadfence();
    }
    __syncthreads();
}

// ---------------------------------------------------------------------------
// GEMM phase: [h | t] = A[M,lda]bf16 @ (BT[1152,ldb]bf16)^T + be
// 64x64 tiles, 1152 tiles looped over G blocks. Same inner loop as r12.
// ---------------------------------------------------------------------------
static __device__ __forceinline__
void gemm_phase(const unsigned short* __restrict__ A, int lda,
                const unsigned short* __restrict__ BT, int ldb,
                const float* __restrict__ bias,
                float* __restrict__ C, float* __restrict__ t,
                int K, unsigned char* smem) {
    unsigned short* As = (unsigned short*)smem;     // 64x32
    unsigned short* Bs = As + 64 * 32;              // 64x32 (8 KB total)
    const int tid = threadIdx.x;
    const int w = tid >> 6, lane = tid & 63;
    const int q = lane >> 4, m16 = lane & 15;
    const int wr = (w >> 1) * 32, wc = (w & 1) * 32;
    const int sr = tid >> 2, sc = (tid & 3) * 8;
    unsigned short* lA0 = As + tid * 8;
    unsigned short* lB0 = Bs + tid * 8;

    for (int tileId = blockIdx.x; tileId < 18 * 64; tileId += G) {
        const int bx = tileId % 18, by = tileId / 18;
        const int br = by * 64, bc = bx * 64;
        const unsigned short* gA0 = A + (size_t)(br + sr) * lda + sc;
        const unsigned short* gB0 = BT + (size_t)(bc + sr) * ldb + sc;
        f32x4 acc[2][2] = {};
        for (int k0 = 0; k0 < K; k0 += 32) {
            __syncthreads();                      // protect prior LDS reads
            ASYNC_CP16(gA0 + k0, lA0);
            ASYNC_CP16(gB0 + k0, lB0);
            __syncthreads();                      // waits DMA (vmcnt drained)
            bf16x8 af[2], bfr[2];
#pragma unroll
            for (int i = 0; i < 2; ++i)
                af[i] = *(const bf16x8*)(As + (wr + 16 * i + m16) * 32 + q * 8);
#pragma unroll
            for (int j = 0; j < 2; ++j)
                bfr[j] = *(const bf16x8*)(Bs + (wc + 16 * j + m16) * 32 + q * 8);
#pragma unroll
            for (int i = 0; i < 2; ++i)
#pragma unroll
                for (int j = 0; j < 2; ++j)
                    acc[i][j] = __builtin_amdgcn_mfma_f32_16x16x32_bf16(af[i], bfr[j], acc[i][j], 0, 0, 0);
        }
#pragma unroll
        for (int i = 0; i < 2; ++i) {
            const int gr = br + wr + 16 * i + q * 4;
#pragma unroll
            for (int j = 0; j < 2; ++j) {
                const int gc = bc + wc + 16 * j + m16;
                if (gc < 1024) {
                    const float b = bias[gc];
#pragma unroll
                    for (int r = 0; r < 4; ++r)
                        C[(size_t)(gr + r) * 1024 + gc] = acc[i][j][r] + b;
                } else if (gc < 1039) {
                    const float b = bias[gc];
#pragma unroll
                    for (int r = 0; r < 4; ++r)
                        t[(size_t)(gr + r) * 15 + (gc - 1024)] = acc[i][j][r] + b;
                }
            }
        }
    }
}

// ---------------------------------------------------------------------------
// Diversity phase: 2048 work units (512 i-tiles x 4 j-chunks) over G blocks.
// 2 i-rows/wave (no spill), flat 15-float LDS rows (0 conflicts).
// ---------------------------------------------------------------------------
static __device__ __forceinline__
void div_phase(const float* __restrict__ t, float* __restrict__ dvp,
               unsigned char* smem, int N) {
    float* tj_s = (float*)smem;                   // 256*15 floats = 15360 B
    const int tid = threadIdx.x;
    const int lane = tid & 63, g = tid >> 6;
    for (int u = blockIdx.x; u < (N / DIV_TI) * DIV_JC; u += G) {
        const int bx = u & 511, jc = u >> 9;
        const int i0 = bx * DIV_TI + g * 2;
        const int jbeg = jc * (N / DIV_JC), jend = jbeg + N / DIV_JC;
        float ti[2][15];
#pragma unroll
        for (int r = 0; r < 2; ++r)
#pragma unroll
            for (int d = 0; d < 15; ++d)
                ti[r][d] = t[(i0 + r) * 15 + d];
        float acc[2][5] = {};
        for (int j0 = jbeg; j0 < jend; j0 += 256) {
            __syncthreads();
#pragma unroll
            for (int it = 0; it < 15; ++it)
                tj_s[it * 256 + tid] = t[j0 * 15 + it * 256 + tid];
            __syncthreads();
#pragma unroll
            for (int m = 0; m < 4; ++m) {
                const float* rp = tj_s + (m * 64 + lane) * 15;
#pragma unroll
                for (int r = 0; r < 2; ++r)
#pragma unroll
                    for (int k = 0; k < 5; ++k) {
                        const float s = fabsf(ti[r][3 * k]     - rp[3 * k])
                                      + fabsf(ti[r][3 * k + 1] - rp[3 * k + 1])
                                      + fabsf(ti[r][3 * k + 2] - rp[3 * k + 2]);
                        acc[r][k] += __expf(-s);
                    }
            }
        }
#pragma unroll
        for (int r = 0; r < 2; ++r)
#pragma unroll
            for (int k = 0; k < 5; ++k)
#pragma unroll
                for (int off = 32; off > 0; off >>= 1)
                    acc[r][k] += __shfl_xor(acc[r][k], off, 64);
        if (lane == 0) {
            float* dst = dvp + (size_t)jc * N * 5;
#pragma unroll
            for (int r = 0; r < 2; ++r)
#pragma unroll
                for (int k = 0; k < 5; ++k)
                    dst[(i0 + r) * 5 + k] = acc[r][k];
        }
    }
}

// ---------------------------------------------------------------------------
// LN phases (mid: -> bf16 hc; head: fused wf dot -> out). Row loop over G.
// ---------------------------------------------------------------------------
static __device__ __forceinline__
void ln_mid_phase(const float* __restrict__ h, const float* __restrict__ dvp,
                  const float* __restrict__ beta, unsigned short* __restrict__ hc_bf,
                  unsigned char* smem, int M) {
    float* red = (float*)smem;                    // red[0..7]
    const int tid = threadIdx.x;
    const int lane = tid & 63, wave = tid >> 6;
    for (int i = blockIdx.x; i < M; i += G) {
        __syncthreads();                          // protect red reuse
        float v[5];
        float s = 0.f, s2 = 0.f;
#pragma unroll
        for (int r = 0; r < 5; ++r) {
            const int c = tid + r * 256;
            if (c < 1029) {
                float xv;
                if (c < 1024) {
                    xv = h[(size_t)i * 1024 + c];
                } else {
                    const int k = c - 1024;
                    xv = 0.f;
#pragma unroll
                    for (int jc = 0; jc < DIV_JC; ++jc)
                        xv += dvp[(size_t)jc * M * 5 + i * 5 + k];
                }
                v[r] = xv; s += xv; s2 += xv * xv;
            }
        }
#pragma unroll
        for (int off = 32; off > 0; off >>= 1) {
            s += __shfl_down(s, off, 64);
            s2 += __shfl_down(s2, off, 64);
        }
        if (lane == 0) { red[wave] = s; red[4 + wave] = s2; }
        __syncthreads();
        const float S = red[0] + red[1] + red[2] + red[3];
        const float S2 = red[4] + red[5] + red[6] + red[7];
        const float mu = S / 1029.f;
        const float var = S2 / 1029.f - mu * mu;
        const float rstd = rsqrtf(var + LN_EPS);
#pragma unroll
        for (int r = 0; r < 5; ++r) {
            const int c = tid + r * 256;
            if (c < 1029) {
                float y = (v[r] - mu) * rstd + beta[c];
                y = (y >= 0.f) ? y : LRELU_ALPHA * y;
                hc_bf[(size_t)i * 1056 + c] = f2bf(y);
            } else if (c < 1056) {
                hc_bf[(size_t)i * 1056 + c] = 0;  // zero K-pad for GEMM1
            }
        }
    }
}

static __device__ __forceinline__
void head_phase(const float* __restrict__ h, const float* __restrict__ dvp,
                const float* __restrict__ beta, const float* __restrict__ wf,
                const float* __restrict__ bfp, float* __restrict__ out,
                unsigned char* smem, int M) {
    float* red = (float*)smem;                    // red[0..11]
    const int tid = threadIdx.x;
    const int lane = tid & 63, wave = tid >> 6;
    for (int i = blockIdx.x; i < M; i += G) {
        __syncthreads();
        float v[5];
        float s = 0.f, s2 = 0.f;
#pragma unroll
        for (int r = 0; r < 5; ++r) {
            const int c = tid + r * 256;
            if (c < 1029) {
                float xv;
                if (c < 1024) {
                    xv = h[(size_t)i * 1024 + c];
                } else {
                    const int k = c - 1024;
                    xv = 0.f;
#pragma unroll
                    for (int jc = 0; jc < DIV_JC; ++jc)
                        xv += dvp[(size_t)jc * M * 5 + i * 5 + k];
                }
                v[r] = xv; s += xv; s2 += xv * xv;
            }
        }
#pragma unroll
        for (int off = 32; off > 0; off >>= 1) {
            s += __shfl_down(s, off, 64);
            s2 += __shfl_down(s2, off, 64);
        }
        if (lane == 0) { red[wave] = s; red[4 + wave] = s2; }
        __syncthreads();
        const float S = red[0] + red[1] + red[2] + red[3];
        const float S2 = red[4] + red[5] + red[6] + red[7];
        const float mu = S / 1029.f;
        const float var = S2 / 1029.f - mu * mu;
        const float rstd = rsqrtf(var + LN_EPS);
        float hsum = 0.f;
#pragma unroll
        for (int r = 0; r < 5; ++r) {
            const int c = tid + r * 256;
            if (c < 1029) {
                float y = (v[r] - mu) * rstd + beta[c];
                y = (y >= 0.f) ? y : LRELU_ALPHA * y;
                hsum += y * wf[c];
            }
        }
#pragma unroll
        for (int off = 32; off > 0; off >>= 1) hsum += __shfl_down(hsum, off, 64);
        if (lane == 0) red[8 + wave] = hsum;
        __syncthreads();
        if (tid == 0) out[i] = red[8] + red[9] + red[10] + red[11] + bfp[0];
    }
}

// ---------------------------------------------------------------------------
// The persistent fused kernel: prep | G0 | div | LN | G1 | div | head,
// separated by 6 grid barriers. Grid MUST be <= co-resident capacity:
// 768 blocks @ 3 blocks/CU (LDS 15.4KB, VGPR capped 170 by launch_bounds).
// ---------------------------------------------------------------------------
__global__ __launch_bounds__(256, 3)
void fused_all(const float* __restrict__ x,
               const float* __restrict__ w0a, const float* __restrict__ b0a,
               const float* __restrict__ w0b, const float* __restrict__ b0b,
               const float* __restrict__ beta0,
               const float* __restrict__ w1a, const float* __restrict__ b1a,
               const float* __restrict__ w1b, const float* __restrict__ b1b,
               const float* __restrict__ beta1,
               const float* __restrict__ wf, const float* __restrict__ bfp,
               float* __restrict__ out, unsigned* __restrict__ cnt,
               float* __restrict__ h, float* __restrict__ t,
               float* __restrict__ dvp,
               float* __restrict__ be0, float* __restrict__ be1,
               unsigned short* __restrict__ x_bf,
               unsigned short* __restrict__ hc_bf,
               unsigned short* __restrict__ bT0,
               unsigned short* __restrict__ bT1) {
    __shared__ __align__(16) unsigned char smem[15360];
    const int tid = threadIdx.x;
    const int lane = tid & 63, w = tid >> 6;

    // ---------------- P0: prep (4011 work units) ----------------
    {
        float (*tile)[33] = (float(*)[33])smem;   // 4224 B
        for (int wb = blockIdx.x; wb < 4011; wb += G) {
            if (wb < 2048) {                      // cast x -> x_bf
                const int i = (wb * 256 + tid) * 4;
                const float4 v = *(const float4*)(x + i);
                ushort4 o;
                o.x = f2bf(v.x); o.y = f2bf(v.y); o.z = f2bf(v.z); o.w = f2bf(v.w);
                *(ushort4*)(x_bf + i) = o;
            } else if (wb < 3616) {               // transpose w0a / w1a
                const int isB1 = (wb >= 2560);
                const int b2 = wb - (isB1 ? 2560 : 2048);
                const int nb = (b2 & 31) * 32, kb = (b2 >> 5) * 32;
                const int tx = tid & 31, ty = tid >> 5;
                const float* W = isB1 ? w1a : w0a;
                const int Kmax = isB1 ? 1029 : 512;
#pragma unroll
                for (int i = 0; i < 4; ++i) {
                    const int k = kb + ty + i * 8;
                    tile[ty + i * 8][tx] = (k < Kmax) ? W[(size_t)k * 1024 + nb + tx] : 0.f;
                }
                __syncthreads();
#pragma unroll
                for (int i = 0; i < 4; ++i) {
                    if (isB1) bT1[(size_t)(nb + ty + i * 8) * 1056 + kb + tx] = f2bf(tile[tx][ty + i * 8]);
                    else      bT0[(size_t)(nb + ty + i * 8) * 512  + kb + tx] = f2bf(tile[tx][ty + i * 8]);
                }
                __syncthreads();                  // tile reuse next iteration
            } else if (wb < 4003) {               // wcomb 0/1
                const int is1 = (wb >= 3745);
                const int b4 = wb - (is1 ? 3745 : 3616);
                const int row = b4 * 4 + w;
                const int F = is1 ? 1029 : 512;
                if (row <= F) {
                    const float* wa = is1 ? w1a : w0a;
                    const float* ba = is1 ? b1a : b0a;
                    const float* wbp = is1 ? w1b : w0b;
                    const float* bbp = is1 ? b1b : b0b;
                    const float* src = (row < F) ? (wa + (size_t)row * 1024) : ba;
                    float acc[15] = {};
                    for (int hh = lane; hh < 1024; hh += 64) {
                        const float a = src[hh];
                        const float* wr = wbp + hh * 15;
#pragma unroll
                        for (int c = 0; c < 15; ++c) acc[c] += a * wr[c];
                    }
#pragma unroll
                    for (int c = 0; c < 15; ++c)
#pragma unroll
                        for (int off = 32; off > 0; off >>= 1)
                            acc[c] += __shfl_xor(acc[c], off, 64);
                    if (lane < 15) {
                        if (row < F) {
                            if (is1) bT1[(size_t)(1024 + lane) * 1056 + row] = f2bf(acc[lane]);
                            else     bT0[(size_t)(1024 + lane) * 512  + row] = f2bf(acc[lane]);
                        } else {
                            if (is1) be1[1024 + lane] = acc[lane] + bbp[lane];
                            else     be0[1024 + lane] = acc[lane] + bbp[lane];
                        }
                    }
                }
            } else {                              // bias copies
                const int b6 = wb - 4003;
                if (b6 < 4) be0[b6 * 256 + tid] = b0a[b6 * 256 + tid];
                else        be1[(b6 - 4) * 256 + tid] = b1a[(b6 - 4) * 256 + tid];
            }
        }
    }
    grid_barrier(cnt + 0);
    // ---------------- P1: GEMM0 (K=512) ----------------
    gemm_phase(x_bf, 512, bT0, 512, be0, h, t, 512, smem);
    grid_barrier(cnt + 1);
    // ---------------- P2: diversity 0 ----------------
    div_phase(t, dvp, smem, 4096);
    grid_barrier(cnt + 2);
    // ---------------- P3: LN 0 -> hc_bf ----------------
    ln_mid_phase(h, dvp, beta0, hc_bf, smem, 4096);
    grid_barrier(cnt + 3);
    // ---------------- P4: GEMM1 (K=1056) ----------------
    gemm_phase(hc_bf, 1056, bT1, 1056, be1, h, t, 1056, smem);
    grid_barrier(cnt + 4);
    // ---------------- P5: diversity 1 ----------------
    div_phase(t, dvp, smem, 4096);
    grid_barrier(cnt + 5);
    // ---------------- P6: LN 1 + head -> out ----------------
    head_phase(h, dvp, beta1, wf, bfp, out, smem, 4096);
}

extern "C" void kernel_launch(void* const* d_in, const int* in_sizes, int n_in,
                              void* d_out, int out_size, void* d_ws, size_t ws_size,
                              hipStream_t stream) {
    const float* x     = (const float*)d_in[0];
    const float* w0a   = (const float*)d_in[1];
    const float* b0a   = (const float*)d_in[2];
    const float* w0b   = (const float*)d_in[3];
    const float* b0b   = (const float*)d_in[4];
    const float* beta0 = (const float*)d_in[5];
    const float* w1a   = (const float*)d_in[6];
    const float* b1a   = (const float*)d_in[7];
    const float* w1b   = (const float*)d_in[8];
    const float* b1b   = (const float*)d_in[9];
    const float* beta1 = (const float*)d_in[10];
    const float* wf    = (const float*)d_in[11];
    const float* bf    = (const float*)d_in[12];
    float* out = (float*)d_out;

    const int M = 4096, NF = 512, CP = 1056;

    // barrier counters: first 256 B of ws (memset to 0 each call)
    unsigned* cnt = (unsigned*)d_ws;
    float* h   = (float*)((char*)d_ws + 256);       // 4096 x 1024
    float* t   = h   + (size_t)M * 1024;            // 4096 x 15
    float* dvp = t   + (size_t)M * 15;              // 4 x 4096 x 5
    float* be0 = dvp + (size_t)DIV_JC * M * 5;      // 1152
    float* be1 = be0 + 1152;                        // 1152
    unsigned short* x_bf  = (unsigned short*)(be1 + 1152);   // 4096 x 512
    unsigned short* hc_bf = x_bf + (size_t)M * NF;           // 4096 x 1056
    unsigned short* bT0   = hc_bf + (size_t)M * CP;          // 1152 x 512
    unsigned short* bT1   = bT0 + (size_t)1152 * NF;         // 1152 x 1056

    hipMemsetAsync(d_ws, 0, 256, stream);
    fused_all<<<G, 256, 0, stream>>>(x, w0a, b0a, w0b, b0b, beta0,
                                     w1a, b1a, w1b, b1b, beta1, wf, bf,
                                     out, cnt, h, t, dvp, be0, be1,
                                     x_bf, hc_bf, bT0, bT1);
}

// Round 14
// 218.059 us; speedup vs baseline: 3.2740x; 3.2740x over previous
//
#include <hip/hip_runtime.h>
#include <hip/hip_bf16.h>

#define LRELU_ALPHA 0.3f
#define LN_EPS 1e-3f

typedef short bf16x8 __attribute__((ext_vector_type(8)));
typedef float f32x4 __attribute__((ext_vector_type(4)));

static __device__ __forceinline__ unsigned short f2bf(float f) {
    union { float f; unsigned u; } v; v.f = f;
    unsigned r = v.u + 0x7fffu + ((v.u >> 16) & 1u);  // RNE
    return (unsigned short)(r >> 16);
}

// async 16B global -> LDS (DMA). LDS dest = wave-uniform base + lane*16.
#define ASYNC_CP16(gsrc, ldst)                                                  \
    __builtin_amdgcn_global_load_lds(                                           \
        (const __attribute__((address_space(1))) unsigned int*)(gsrc),          \
        (__attribute__((address_space(3))) unsigned int*)(ldst), 16, 0, 0)

#define NE 1152   // extended B-rows: 1024 hidden + 15 fused-skinny + pad

// ---------------------------------------------------------------------------
// Fused prep kernel (r12): cast x, transpose big weights, weight-combine
// skinny into B rows 1024..1038, extended biases.
// ---------------------------------------------------------------------------
__global__ void prep_kernel(const float* __restrict__ x,
                            const float* __restrict__ w0a, const float* __restrict__ b0a,
                            const float* __restrict__ w0b, const float* __restrict__ b0b,
                            const float* __restrict__ w1a, const float* __restrict__ b1a,
                            const float* __restrict__ w1b, const float* __restrict__ b1b,
                            unsigned short* __restrict__ x_bf,
                            unsigned short* __restrict__ bT0, unsigned short* __restrict__ bT1,
                            float* __restrict__ be0, float* __restrict__ be1) {
    __shared__ float tile[32][33];
    const int b = blockIdx.x, tid = threadIdx.x;

    if (b < 2048) {                       // ---- cast x ----
        const int i = (b * 256 + tid) * 4;
        const float4 v = *(const float4*)(x + i);
        ushort4 o;
        o.x = f2bf(v.x); o.y = f2bf(v.y); o.z = f2bf(v.z); o.w = f2bf(v.w);
        *(ushort4*)(x_bf + i) = o;
        return;
    }
    if (b < 2560) {                       // ---- transpose w0a -> bT0 ----
        const int b2 = b - 2048;
        const int nb = (b2 & 31) * 32, kb = (b2 >> 5) * 32;
        const int tx = tid & 31, ty = tid >> 5;       // 32 x 8
#pragma unroll
        for (int i = 0; i < 4; ++i)
            tile[ty + i * 8][tx] = w0a[(size_t)(kb + ty + i * 8) * 1024 + nb + tx];
        __syncthreads();
#pragma unroll
        for (int i = 0; i < 4; ++i)
            bT0[(size_t)(nb + ty + i * 8) * 512 + kb + tx] = f2bf(tile[tx][ty + i * 8]);
        return;
    }
    if (b < 3616) {                       // ---- transpose w1a -> bT1 ----
        const int b3 = b - 2560;
        const int nb = (b3 & 31) * 32, kb = (b3 >> 5) * 32;   // kb up to 1055
        const int tx = tid & 31, ty = tid >> 5;
#pragma unroll
        for (int i = 0; i < 4; ++i) {
            const int k = kb + ty + i * 8;
            tile[ty + i * 8][tx] = (k < 1029) ? w1a[(size_t)k * 1024 + nb + tx] : 0.f;
        }
        __syncthreads();
#pragma unroll
        for (int i = 0; i < 4; ++i)
            bT1[(size_t)(nb + ty + i * 8) * 1056 + kb + tx] = f2bf(tile[tx][ty + i * 8]);
        return;
    }
    if (b < 4003) {                       // ---- wcomb 0/1 ----
        const int is1 = (b >= 3745);
        const int b4 = b - (is1 ? 3745 : 3616);
        const int w = tid >> 6, lane = tid & 63;
        const int row = b4 * 4 + w;
        const int F = is1 ? 1029 : 512;
        if (row > F) return;
        const float* wa = is1 ? w1a : w0a;
        const float* ba = is1 ? b1a : b0a;
        const float* wb = is1 ? w1b : w0b;
        const float* bb = is1 ? b1b : b0b;
        const float* src = (row < F) ? (wa + (size_t)row * 1024) : ba;
        float acc[15] = {};
        for (int h = lane; h < 1024; h += 64) {
            const float a = src[h];
            const float* wr = wb + h * 15;
#pragma unroll
            for (int c = 0; c < 15; ++c) acc[c] += a * wr[c];
        }
#pragma unroll
        for (int c = 0; c < 15; ++c)
#pragma unroll
            for (int off = 32; off > 0; off >>= 1) acc[c] += __shfl_xor(acc[c], off, 64);
        if (lane < 15) {
            if (row < F) {
                if (is1) bT1[(size_t)(1024 + lane) * 1056 + row] = f2bf(acc[lane]);
                else     bT0[(size_t)(1024 + lane) * 512  + row] = f2bf(acc[lane]);
            } else {
                if (is1) be1[1024 + lane] = acc[lane] + bb[lane];
                else     be0[1024 + lane] = acc[lane] + bb[lane];
            }
        }
        return;
    }
    {                                     // ---- bias copies ----
        const int b6 = b - 4003;
        if (b6 < 4) be0[b6 * 256 + tid] = b0a[b6 * 256 + tid];
        else        be1[(b6 - 4) * 256 + tid] = b1a[(b6 - 4) * 256 + tid];
    }
}

// ---------------------------------------------------------------------------
// bf16 MFMA GEMM: [h | t] = A[M,lda]bf16 @ (BT[NE,ldb]bf16)^T + be
// 64x64 tile, grid (18,64)=1152 blocks = 4.5 blocks/CU (r12 TLP config),
// now with DOUBLE-BUFFERED LDS ping-pong: prefetch tile k+1 into the idle
// buffer right after the barrier, compute from the current buffer, flip.
// One barrier per BK=32 iteration instead of two (GEMM1: 66 -> 34 drains),
// and the DMA latency overlaps the ds_read+MFMA stage. r13's persistent
// variant spilled (VGPR=64, 50MB scratch) — multi-kernel isolation kept.
// LDS 16 KB. Epilogue: cols<1024 -> h (ld 1024); 1024..1038 -> t (ld 15).
// ---------------------------------------------------------------------------
__global__ __launch_bounds__(256)
void mfma_gemm(const unsigned short* __restrict__ A, int lda,
               const unsigned short* __restrict__ BT, int ldb,
               const float* __restrict__ bias, float* __restrict__ C,
               float* __restrict__ t, int K) {
    __shared__ unsigned short As[2][64 * 32];    // 2 x 4 KB
    __shared__ unsigned short Bs[2][64 * 32];    // 2 x 4 KB
    const int tid = threadIdx.x;
    const int w = tid >> 6, lane = tid & 63;
    const int q = lane >> 4, m16 = lane & 15;
    const int wr = (w >> 1) * 32, wc = (w & 1) * 32;
    const int br = blockIdx.y * 64, bc = blockIdx.x * 64;

    const int sr = tid >> 2;          // staging row 0..63
    const int sc = (tid & 3) * 8;     // staging col (elements)

    const unsigned short* gA = A + (size_t)(br + sr) * lda + sc;
    const unsigned short* gB = BT + (size_t)(bc + sr) * ldb + sc;

    // prologue: prefetch k0=0 into buffer 0
    ASYNC_CP16(gA, &As[0][tid * 8]);
    ASYNC_CP16(gB, &Bs[0][tid * 8]);

    f32x4 acc[2][2] = {};
    int cur = 0;

    for (int k0 = 0; k0 < K; k0 += 32) {
        __syncthreads();              // drains DMA into buf[cur]; orders prior reads
        const int nk = k0 + 32;
        if (nk < K) {                 // prefetch next tile into the idle buffer
            ASYNC_CP16(gA + nk, &As[cur ^ 1][tid * 8]);
            ASYNC_CP16(gB + nk, &Bs[cur ^ 1][tid * 8]);
        }
        bf16x8 af[2], bfr[2];
#pragma unroll
        for (int i = 0; i < 2; ++i)
            af[i] = *(const bf16x8*)(&As[cur][(wr + 16 * i + m16) * 32 + q * 8]);
#pragma unroll
        for (int j = 0; j < 2; ++j)
            bfr[j] = *(const bf16x8*)(&Bs[cur][(wc + 16 * j + m16) * 32 + q * 8]);
#pragma unroll
        for (int i = 0; i < 2; ++i)
#pragma unroll
            for (int j = 0; j < 2; ++j)
                acc[i][j] = __builtin_amdgcn_mfma_f32_16x16x32_bf16(af[i], bfr[j], acc[i][j], 0, 0, 0);
        cur ^= 1;
    }

#pragma unroll
    for (int i = 0; i < 2; ++i) {
        const int gr = br + wr + 16 * i + q * 4;
#pragma unroll
        for (int j = 0; j < 2; ++j) {
            const int gc = bc + wc + 16 * j + m16;
            if (gc < 1024) {
                const float b = bias[gc];
#pragma unroll
                for (int r = 0; r < 4; ++r)
                    C[(size_t)(gr + r) * 1024 + gc] = acc[i][j][r] + b;
            } else if (gc < 1039) {
                const float b = bias[gc];
#pragma unroll
                for (int r = 0; r < 4; ++r)
                    t[(size_t)(gr + r) * 15 + (gc - 1024)] = acc[i][j][r] + b;
            }
        }
    }
}

// ---------------------------------------------------------------------------
// Batch diversity (r11/r12 config): t (N,15 contiguous) -> dv_part.
// 2 i-rows/wave (no spill), flat 15-float LDS rows (0 conflicts),
// grid (512,4)=2048 blocks -> 8 blocks/CU.
// ---------------------------------------------------------------------------
#define DIV_TI 8
#define DIV_JC 4
__global__ __launch_bounds__(256)
void diversity_kernel(const float* __restrict__ t, float* __restrict__ dv_part, int N) {
    const int tid = threadIdx.x;
    const int lane = tid & 63;
    const int g = tid >> 6;
    const int i0 = blockIdx.x * DIV_TI + g * 2;
    const int jbeg = blockIdx.y * (N / DIV_JC);
    const int jend = jbeg + N / DIV_JC;

    float ti[2][15];
#pragma unroll
    for (int r = 0; r < 2; ++r)
#pragma unroll
        for (int d = 0; d < 15; ++d)
            ti[r][d] = t[(i0 + r) * 15 + d];

    float acc[2][5] = {};

    __shared__ float tj_s[256 * 15];
    for (int j0 = jbeg; j0 < jend; j0 += 256) {
        __syncthreads();
#pragma unroll
        for (int it = 0; it < 15; ++it)
            tj_s[it * 256 + tid] = t[j0 * 15 + it * 256 + tid];  // straight copy
        __syncthreads();
#pragma unroll
        for (int m = 0; m < 4; ++m) {
            const float* rp = tj_s + (m * 64 + lane) * 15;
#pragma unroll
            for (int r = 0; r < 2; ++r) {
#pragma unroll
                for (int k = 0; k < 5; ++k) {
                    const float s = fabsf(ti[r][3 * k]     - rp[3 * k])
                                  + fabsf(ti[r][3 * k + 1] - rp[3 * k + 1])
                                  + fabsf(ti[r][3 * k + 2] - rp[3 * k + 2]);
                    acc[r][k] += __expf(-s);
                }
            }
        }
    }

#pragma unroll
    for (int r = 0; r < 2; ++r)
#pragma unroll
        for (int k = 0; k < 5; ++k)
#pragma unroll
            for (int off = 32; off > 0; off >>= 1)
                acc[r][k] += __shfl_xor(acc[r][k], off, 64);

    if (lane == 0) {
        float* dst = dv_part + (size_t)blockIdx.y * N * 5;
#pragma unroll
        for (int r = 0; r < 2; ++r)
#pragma unroll
            for (int k = 0; k < 5; ++k)
                dst[(i0 + r) * 5 + k] = acc[r][k];
    }
}

// ---------------------------------------------------------------------------
// concat([h, sum(dv_part)]) -> LN(center) -> LeakyReLU -> bf16 (M x Cp)
// ---------------------------------------------------------------------------
__global__ void ln_lrelu_mid(const float* __restrict__ h,
                             const float* __restrict__ dv_part,
                             const float* __restrict__ beta,
                             unsigned short* __restrict__ out_bf,
                             int H, int D, int Cp, int M) {
    const int i = blockIdx.x;
    const int tid = threadIdx.x;
    const int C = H + D;
    float v[5];
    float s = 0.f, s2 = 0.f;
#pragma unroll
    for (int r = 0; r < 5; ++r) {
        const int c = tid + r * 256;
        if (c < C) {
            float x;
            if (c < H) {
                x = h[(size_t)i * H + c];
            } else {
                const int k = c - H;
                x = 0.f;
#pragma unroll
                for (int jc = 0; jc < DIV_JC; ++jc)
                    x += dv_part[(size_t)jc * M * D + i * D + k];
            }
            v[r] = x; s += x; s2 += x * x;
        }
    }
    __shared__ float rs[4], rs2[4];
    const int lane = tid & 63, wave = tid >> 6;
#pragma unroll
    for (int off = 32; off > 0; off >>= 1) {
        s += __shfl_down(s, off, 64);
        s2 += __shfl_down(s2, off, 64);
    }
    if (lane == 0) { rs[wave] = s; rs2[wave] = s2; }
    __syncthreads();
    const float S = rs[0] + rs[1] + rs[2] + rs[3];
    const float S2 = rs2[0] + rs2[1] + rs2[2] + rs2[3];
    const float mu = S / (float)C;
    const float var = S2 / (float)C - mu * mu;
    const float rstd = rsqrtf(var + LN_EPS);
#pragma unroll
    for (int r = 0; r < 5; ++r) {
        const int c = tid + r * 256;
        if (c < C) {
            float y = (v[r] - mu) * rstd + beta[c];
            y = (y >= 0.f) ? y : LRELU_ALPHA * y;
            out_bf[(size_t)i * Cp + c] = f2bf(y);
        } else if (c < Cp) {
            out_bf[(size_t)i * Cp + c] = 0;  // zero K-pad for next MFMA GEMM
        }
    }
}

// ---------------------------------------------------------------------------
// Final: concat -> LN -> LeakyReLU -> fused head dot: out[i] = y.wf + bf
// ---------------------------------------------------------------------------
__global__ void ln_lrelu_head(const float* __restrict__ h,
                              const float* __restrict__ dv_part,
                              const float* __restrict__ beta, const float* __restrict__ wf,
                              const float* __restrict__ bfp, float* __restrict__ out,
                              int H, int D, int M) {
    const int i = blockIdx.x;
    const int tid = threadIdx.x;
    const int C = H + D;
    float v[5];
    float s = 0.f, s2 = 0.f;
#pragma unroll
    for (int r = 0; r < 5; ++r) {
        const int c = tid + r * 256;
        if (c < C) {
            float x;
            if (c < H) {
                x = h[(size_t)i * H + c];
            } else {
                const int k = c - H;
                x = 0.f;
#pragma unroll
                for (int jc = 0; jc < DIV_JC; ++jc)
                    x += dv_part[(size_t)jc * M * D + i * D + k];
            }
            v[r] = x; s += x; s2 += x * x;
        }
    }
    __shared__ float rs[4], rs2[4], rh[4];
    const int lane = tid & 63, wave = tid >> 6;
#pragma unroll
    for (int off = 32; off > 0; off >>= 1) {
        s += __shfl_down(s, off, 64);
        s2 += __shfl_down(s2, off, 64);
    }
    if (lane == 0) { rs[wave] = s; rs2[wave] = s2; }
    __syncthreads();
    const float S = rs[0] + rs[1] + rs[2] + rs[3];
    const float S2 = rs2[0] + rs2[1] + rs2[2] + rs2[3];
    const float mu = S / (float)C;
    const float var = S2 / (float)C - mu * mu;
    const float rstd = rsqrtf(var + LN_EPS);
    float hsum = 0.f;
#pragma unroll
    for (int r = 0; r < 5; ++r) {
        const int c = tid + r * 256;
        if (c < C) {
            float y = (v[r] - mu) * rstd + beta[c];
            y = (y >= 0.f) ? y : LRELU_ALPHA * y;
            hsum += y * wf[c];
        }
    }
#pragma unroll
    for (int off = 32; off > 0; off >>= 1) hsum += __shfl_down(hsum, off, 64);
    if (lane == 0) rh[wave] = hsum;
    __syncthreads();
    if (tid == 0) out[i] = rh[0] + rh[1] + rh[2] + rh[3] + bfp[0];
}

extern "C" void kernel_launch(void* const* d_in, const int* in_sizes, int n_in,
                              void* d_out, int out_size, void* d_ws, size_t ws_size,
                              hipStream_t stream) {
    const float* x     = (const float*)d_in[0];
    const float* w0a   = (const float*)d_in[1];
    const float* b0a   = (const float*)d_in[2];
    const float* w0b   = (const float*)d_in[3];
    const float* b0b   = (const float*)d_in[4];
    const float* beta0 = (const float*)d_in[5];
    const float* w1a   = (const float*)d_in[6];
    const float* b1a   = (const float*)d_in[7];
    const float* w1b   = (const float*)d_in[8];
    const float* b1b   = (const float*)d_in[9];
    const float* beta1 = (const float*)d_in[10];
    const float* wf    = (const float*)d_in[11];
    const float* bf    = (const float*)d_in[12];
    float* out = (float*)d_out;

    const int M = 4096, NF = 512, HID = 1024, CP = 1056;

    // fp32 workspace (all offsets multiple-of-4 floats -> 16B aligned)
    float* h   = (float*)d_ws;                      // 4096 x 1024
    float* t   = h   + (size_t)M * HID;             // 4096 x 15 (contiguous)
    float* dvp = t   + (size_t)M * 15;              // DIV_JC x 4096 x 5
    float* be0 = dvp + (size_t)DIV_JC * M * 5;      // 1152
    float* be1 = be0 + NE;                          // 1152
    // bf16 workspace (16B-aligned)
    unsigned short* x_bf = (unsigned short*)(be1 + NE);              // 4096 x 512
    unsigned short* hc_bf = x_bf + (size_t)M * NF;                   // 4096 x 1056
    unsigned short* bT0   = hc_bf + (size_t)M * CP;                  // 1152 x 512
    unsigned short* bT1   = bT0 + (size_t)NE * NF;                   // 1152 x 1056

    // ---- fused prep ----
    prep_kernel<<<4011, 256, 0, stream>>>(x, w0a, b0a, w0b, b0b, w1a, b1a, w1b, b1b,
                                          x_bf, bT0, bT1, be0, be1);

    // ---- layer 0: GEMM writes h (cols<1024) and compact t (cols 1024..1038) ----
    mfma_gemm<<<dim3(NE / 64, M / 64), 256, 0, stream>>>(x_bf, NF, bT0, NF, be0, h, t, NF);
    diversity_kernel<<<dim3(M / DIV_TI, DIV_JC), 256, 0, stream>>>(t, dvp, M);
    ln_lrelu_mid<<<M, 256, 0, stream>>>(h, dvp, beta0, hc_bf, HID, 5, CP, M);

    // ---- layer 1 ----
    mfma_gemm<<<dim3(NE / 64, M / 64), 256, 0, stream>>>(hc_bf, CP, bT1, CP, be1, h, t, CP);
    diversity_kernel<<<dim3(M / DIV_TI, DIV_JC), 256, 0, stream>>>(t, dvp, M);
    ln_lrelu_head<<<M, 256, 0, stream>>>(h, dvp, beta1, wf, bf, out, HID, 5, M);
}